// Round 5
// baseline (475.696 us; speedup 1.0000x reference)
//
#include <hip/hip_runtime.h>

typedef short s16x8 __attribute__((ext_vector_type(8)));
typedef float f32x4 __attribute__((ext_vector_type(4)));

#define LDW 136    // padded LDS row stride in shorts (128 + 8)
#define CAP 10240  // padded bin segment capacity (mean 8192, sigma~90 -> 22 sigma headroom)
#define MAXB 384   // max 3*NB bins supported (N <= 131072; also src must fit 20 bits)

__device__ __forceinline__ unsigned short f2bf(float x) {
    unsigned int u = __builtin_bit_cast(unsigned int, x);
    u = (u + 0x7fffu + ((u >> 16) & 1u)) >> 16;   // RNE
    return (unsigned short)u;
}
__device__ __forceinline__ float bf2f(unsigned int lo) {
    return __builtin_bit_cast(float, lo << 16);
}

// ---- W fp32 -> bf16, transposed: WbfT[which][n][k] = bf16(W[which][k][n]) ----
__global__ __launch_bounds__(256) void wconv_kernel(const float* __restrict__ W1,
                                                    const float* __restrict__ W2,
                                                    unsigned short* __restrict__ WbfT,
                                                    int total) {
    int idx = blockIdx.x * 256 + threadIdx.x;
    if (idx >= total) return;
    int which = idx >> 14;
    int k = (idx >> 7) & 127;
    int n = idx & 127;
    int outi = (idx & ~16383) | (n << 7) | k;
    const float* W = (which < 3) ? (W1 + (size_t)which * 16384)
                                 : (W2 + (size_t)(which - 3) * 16384);
    WbfT[outi] = f2bf(W[k * 128 + n]);
}

// ---- FUSED MEGA: blocks [0,gb) = layer-1 gemm3 (fp32 input, UNSCALED T out);
//      blocks [gb,..) = dual src+dst binning (edges held in regs, one pass) ----
__global__ __launch_bounds__(256) void gemm3_binA(const float* __restrict__ Xp,
                                                  const unsigned short* __restrict__ WbfT,
                                                  unsigned short* __restrict__ T,
                                                  int nrows, int gb,
                                                  const int* __restrict__ src,
                                                  const int* __restrict__ dst,
                                                  int* __restrict__ bincntO,
                                                  int* __restrict__ bincntD,
                                                  unsigned short* __restrict__ srcbin,
                                                  unsigned int* __restrict__ pair,
                                                  int RE, int E, int N, int NB) {
    __shared__ unsigned short Xl[64 * LDW];
    __shared__ unsigned short Wl[128 * LDW];
    int tid = threadIdx.x;

    if ((int)blockIdx.x >= gb) {
        // ---- dual-binning branch: src-bins (ushort s&1023) + dst-bins (packed u32) ----
        int* histS = (int*)Xl;            // MAXB ints
        int* histD = histS + MAXB;        // MAXB ints (fits in Xl: 3KB << 17.4KB)
        int ebase = ((int)blockIdx.x - gb) * 4096;
        int NB3 = 3 * NB;
        int vs[16], vd[16];
        for (int t = tid; t < 2 * MAXB; t += 256) histS[t] = 0;
        __syncthreads();
#pragma unroll
        for (int j = 0; j < 16; ++j) {
            int i = ebase + j * 256 + tid;
            vs[j] = 0; vd[j] = 0;
            if (i < RE) {
                vs[j] = src[i]; vd[j] = dst[i];
                int r = (i >= 2 * E) ? 2 : ((i >= E) ? 1 : 0);
                atomicAdd(&histS[r * NB + (vs[j] >> 10)], 1);
                atomicAdd(&histD[r * NB + (vd[j] >> 10)], 1);
            }
        }
        __syncthreads();
        for (int t = tid; t < NB3; t += 256) {
            int cS = histS[t]; histS[t] = cS ? atomicAdd(&bincntO[t], cS) : 0;
            int cD = histD[t]; histD[t] = cD ? atomicAdd(&bincntD[t], cD) : 0;
        }
        __syncthreads();
#pragma unroll
        for (int j = 0; j < 16; ++j) {
            int i = ebase + j * 256 + tid;
            if (i < RE) {
                int r = (i >= 2 * E) ? 2 : ((i >= E) ? 1 : 0);
                int gS = r * NB + (vs[j] >> 10);
                int pS = atomicAdd(&histS[gS], 1);
                if (pS < CAP) srcbin[(size_t)gS * CAP + pS] = (unsigned short)(vs[j] & 1023);
                int gD = r * NB + (vd[j] >> 10);
                int pD = atomicAdd(&histD[gD], 1);
                if (pD < CAP)
                    pair[(size_t)gD * CAP + pD] =
                        ((unsigned)(vd[j] & 1023) << 20) | (unsigned)vs[j];
            }
        }
        return;
    }

    // ---- gemm3 layer-1 branch (T written UNSCALED; normO applied in gather1) ----
    int row0 = blockIdx.x * 64;
#pragma unroll
    for (int j = 0; j < 8; ++j) {
        int f4 = tid + j * 256;
        int row = f4 >> 5;
        int k0 = (f4 & 31) * 4;
        int gr = row0 + row;
        float4 v = make_float4(0.f, 0.f, 0.f, 0.f);
        if (gr < nrows) v = ((const float4*)Xp)[(size_t)gr * 32 + (f4 & 31)];
        unsigned long long pk = (unsigned long long)f2bf(v.x)
                              | ((unsigned long long)f2bf(v.y) << 16)
                              | ((unsigned long long)f2bf(v.z) << 32)
                              | ((unsigned long long)f2bf(v.w) << 48);
        *(unsigned long long*)(&Xl[row * LDW + k0]) = pk;
    }
#pragma unroll
    for (int j = 0; j < 8; ++j) {
        int i = tid + j * 256;            // 2048 uint4 chunks = 128*128 shorts
        int row = i >> 4, c0 = (i & 15) * 8;
        *(uint4*)(Wl + row * LDW + c0) = ((const uint4*)WbfT)[i];
    }
    __syncthreads();

    int wave = tid >> 6, lane = tid & 63;
    int laneM = lane & 15, quad = lane >> 4;
    int m0 = wave * 16;

    s16x8 afr[4];
#pragma unroll
    for (int ks = 0; ks < 4; ++ks)
        afr[ks] = *(const s16x8*)(Xl + (m0 + laneM) * LDW + ks * 32 + quad * 8);

    for (int r = 0; r < 3; ++r) {
        f32x4 acc[8];
#pragma unroll
        for (int ct = 0; ct < 8; ++ct) acc[ct] = (f32x4){0.f, 0.f, 0.f, 0.f};
#pragma unroll
        for (int ks = 0; ks < 4; ++ks) {
            int k = ks * 32 + quad * 8;
#pragma unroll
            for (int ct = 0; ct < 8; ++ct) {
                s16x8 b = *(const s16x8*)(Wl + (ct * 16 + laneM) * LDW + k);
                acc[ct] = __builtin_amdgcn_mfma_f32_16x16x32_bf16(afr[ks], b, acc[ct], 0, 0, 0);
            }
        }
        unsigned short* Tr = T + (size_t)r * nrows * 128;
#pragma unroll
        for (int i = 0; i < 4; ++i) {
            int gr = row0 + m0 + quad * 4 + i;
            if (gr < nrows) {
#pragma unroll
                for (int ct = 0; ct < 8; ++ct)
                    Tr[(size_t)gr * 128 + ct * 16 + laneM] = f2bf(acc[ct][i]);
            }
        }
        if (r < 2) {
            __syncthreads();
#pragma unroll
            for (int j = 0; j < 8; ++j) {
                int i = tid + j * 256;
                int row = i >> 4, c0 = (i & 15) * 8;
                *(uint4*)(Wl + row * LDW + c0) =
                    ((const uint4*)(WbfT + (size_t)(r + 1) * 16384))[i];
            }
            __syncthreads();
        }
    }
}

// ---- FUSED: blocks [0,NB3) = out-degree histogram -> normO;
//      blocks [NB3,2*NB3) = per-(r,bin) LDS counting sort -> cntI/normI/offs/bucket ----
__global__ __launch_bounds__(256) void histsort_kernel(const unsigned short* __restrict__ srcbin,
                                                       const int* __restrict__ bincntO,
                                                       const unsigned int* __restrict__ pair,
                                                       const int* __restrict__ bincntD,
                                                       float* __restrict__ normO,
                                                       unsigned int* __restrict__ cntI,
                                                       float* __restrict__ normI,
                                                       int* __restrict__ offs,
                                                       int* __restrict__ bucket,
                                                       int N, int NB, int NB3) {
    __shared__ int lcnt[1024], lofs[1024], lcur[1024];
    __shared__ int ws[4];
    int tid = threadIdx.x;

    if ((int)blockIdx.x < NB3) {
        // ---- out-degree histogram branch ----
        int b = blockIdx.x;
        for (int i = tid; i < 1024; i += 256) lcnt[i] = 0;
        __syncthreads();
        int len = bincntO[b]; if (len > CAP) len = CAP;
        const unsigned short* seg = srcbin + (size_t)b * CAP;
        for (int e = tid; e < len; e += 256)
            atomicAdd(&lcnt[seg[e]], 1);
        __syncthreads();
        int r = b / NB, bin = b - r * NB;
        int node0 = bin << 10;
        for (int i = tid; i < 1024; i += 256) {
            int node = node0 + i;
            if (node < N)
                normO[(size_t)r * N + node] = rsqrtf(fmaxf((float)lcnt[i], 1.0f));
        }
        return;
    }

    // ---- counting-sort branch ----
    int b = blockIdx.x - NB3;
    for (int i = tid; i < 1024; i += 256) { lcnt[i] = 0; lcur[i] = 0; }
    __syncthreads();
    int len = bincntD[b]; if (len > CAP) len = CAP;
    const unsigned int* seg = pair + (size_t)b * CAP;
    for (int e = tid; e < len; e += 256)
        atomicAdd(&lcnt[seg[e] >> 20], 1);
    __syncthreads();
    // exclusive scan of lcnt[1024] -> lofs
    int i0 = tid * 4;
    int a0 = lcnt[i0], a1 = lcnt[i0 + 1], a2 = lcnt[i0 + 2], a3 = lcnt[i0 + 3];
    int tot = a0 + a1 + a2 + a3;
    int lane = tid & 63, w = tid >> 6;
    int x = tot;
#pragma unroll
    for (int d = 1; d < 64; d <<= 1) { int y = __shfl_up(x, d, 64); if (lane >= d) x += y; }
    if (lane == 63) ws[w] = x;
    __syncthreads();
    int wbase = 0;
    for (int k = 0; k < 4; ++k) if (k < w) wbase += ws[k];
    int pre = wbase + x - tot;
    lofs[i0] = pre;
    lofs[i0 + 1] = pre + a0;
    lofs[i0 + 2] = pre + a0 + a1;
    lofs[i0 + 3] = pre + a0 + a1 + a2;
    __syncthreads();
    int r = b / NB, bin = b - r * NB;
    int node0 = bin << 10;
    int base = b * CAP;
    for (int i = tid; i < 1024; i += 256) {
        int node = node0 + i;
        if (node < N) {
            int c = lcnt[i];
            cntI[(size_t)r * N + node]  = (unsigned int)c;
            normI[(size_t)r * N + node] = rsqrtf(fmaxf((float)c, 1.0f));
            offs[(size_t)r * N + node]  = base + lofs[i];
        }
    }
    for (int e = tid; e < len; e += 256) {
        unsigned int p = seg[e];
        int dl = p >> 20;
        int lr = atomicAdd(&lcur[dl], 1);
        bucket[(size_t)base + lofs[dl] + lr] = (int)(p & 0xFFFFFu);
    }
}

// ---- layer-2 gemm (bf16 input, normO applied in epilogue as before) ----
__global__ __launch_bounds__(256) void gemm3_bf16(const unsigned short* __restrict__ Xp,
                                                  const unsigned short* __restrict__ WbfT,
                                                  const float* __restrict__ normO,
                                                  unsigned short* __restrict__ T,
                                                  int nrows) {
    __shared__ unsigned short Xl[64 * LDW];
    __shared__ unsigned short Wl[128 * LDW];
    int tid = threadIdx.x;
    int row0 = blockIdx.x * 64;

#pragma unroll
    for (int j = 0; j < 8; ++j) {
        int f4 = tid + j * 256;
        int row = f4 >> 5;
        int k0 = (f4 & 31) * 4;
        int gr = row0 + row;
        uint2 v = make_uint2(0u, 0u);
        if (gr < nrows) v = ((const uint2*)Xp)[(size_t)gr * 32 + (f4 & 31)];
        *(uint2*)(&Xl[row * LDW + k0]) = v;
    }
#pragma unroll
    for (int j = 0; j < 8; ++j) {
        int i = tid + j * 256;
        int row = i >> 4, c0 = (i & 15) * 8;
        *(uint4*)(Wl + row * LDW + c0) = ((const uint4*)WbfT)[i];
    }
    __syncthreads();

    int wave = tid >> 6, lane = tid & 63;
    int laneM = lane & 15, quad = lane >> 4;
    int m0 = wave * 16;

    s16x8 afr[4];
#pragma unroll
    for (int ks = 0; ks < 4; ++ks)
        afr[ks] = *(const s16x8*)(Xl + (m0 + laneM) * LDW + ks * 32 + quad * 8);

    for (int r = 0; r < 3; ++r) {
        f32x4 acc[8];
#pragma unroll
        for (int ct = 0; ct < 8; ++ct) acc[ct] = (f32x4){0.f, 0.f, 0.f, 0.f};
#pragma unroll
        for (int ks = 0; ks < 4; ++ks) {
            int k = ks * 32 + quad * 8;
#pragma unroll
            for (int ct = 0; ct < 8; ++ct) {
                s16x8 b = *(const s16x8*)(Wl + (ct * 16 + laneM) * LDW + k);
                acc[ct] = __builtin_amdgcn_mfma_f32_16x16x32_bf16(afr[ks], b, acc[ct], 0, 0, 0);
            }
        }
        unsigned short* Tr = T + (size_t)r * nrows * 128;
        const float* nrm = normO + (size_t)r * nrows;
#pragma unroll
        for (int i = 0; i < 4; ++i) {
            int gr = row0 + m0 + quad * 4 + i;
            if (gr < nrows) {
                float sc = nrm[gr];
#pragma unroll
                for (int ct = 0; ct < 8; ++ct)
                    Tr[(size_t)gr * 128 + ct * 16 + laneM] = f2bf(acc[ct][i] * sc);
            }
        }
        if (r < 2) {
            __syncthreads();
#pragma unroll
            for (int j = 0; j < 8; ++j) {
                int i = tid + j * 256;
                int row = i >> 4, c0 = (i & 15) * 8;
                *(uint4*)(Wl + row * LDW + c0) =
                    ((const uint4*)(WbfT + (size_t)(r + 1) * 16384))[i];
            }
            __syncthreads();
        }
    }
}

// ---- gather: one wave per dst node; lanes split 2x32 so each uint2 wave-load
// fetches TWO 256B rows (2 edges/instr, 8 loads in flight covering 16 edges).
// NORMO: apply per-src normO (layer 1, where T is unscaled). ----
template <bool RELU, bool BF16OUT, bool NORMO>
__global__ __launch_bounds__(256) void gather_kernel(const unsigned short* __restrict__ T, // [R][N][128]
                                                     const int* __restrict__ bucket,       // padded bins
                                                     const int* __restrict__ offs,         // [R][N] ABSOLUTE
                                                     const unsigned int* __restrict__ cnt, // [R][N]
                                                     const float* __restrict__ normI,      // [R][N]
                                                     const float* __restrict__ normO,      // [R][N]
                                                     const float* __restrict__ bias,       // [R][128]
                                                     void* __restrict__ out,
                                                     int N) {
    int n = blockIdx.x * 4 + (threadIdx.x >> 6);
    if (n >= N) return;
    int lane = threadIdx.x & 63;
    int half = lane >> 5, q = lane & 31;      // lane covers cols 4q..4q+3 of row 'half'
    float a0 = 0.f, a1 = 0.f, a2 = 0.f, a3 = 0.f;
#pragma unroll
    for (int r = 0; r < 3; ++r) {
        int start = offs[(size_t)r * N + n];
        int c = (int)cnt[(size_t)r * N + n];
        const uint2* Tr = (const uint2*)(T + (size_t)r * N * 128);
        const float* nO = normO + (size_t)r * N;
        const int* bk = bucket + start;
        float p0 = 0.f, p1 = 0.f, p2 = 0.f, p3 = 0.f;
        for (int base = 0; base < c; base += 64) {
            int m = min(64, c - base);
            int id = (lane < m) ? bk[base + lane] : 0;
            for (int jj = 0; jj < m; jj += 16) {
                uint2 v[8]; float sc[8];
#pragma unroll
                for (int u = 0; u < 8; ++u) {
                    int e = jj + 2 * u + half;
                    int s2 = __shfl(id, e, 64);
                    bool ok = e < m;
                    v[u] = ok ? Tr[(size_t)s2 * 32 + q] : make_uint2(0u, 0u);
                    if (NORMO) sc[u] = ok ? nO[s2] : 0.f;
                }
#pragma unroll
                for (int u = 0; u < 8; ++u) {
                    float f0 = bf2f(v[u].x & 0xffffu), f1 = bf2f(v[u].x >> 16);
                    float f2 = bf2f(v[u].y & 0xffffu), f3 = bf2f(v[u].y >> 16);
                    if (NORMO) {
                        p0 = fmaf(sc[u], f0, p0); p1 = fmaf(sc[u], f1, p1);
                        p2 = fmaf(sc[u], f2, p2); p3 = fmaf(sc[u], f3, p3);
                    } else {
                        p0 += f0; p1 += f1; p2 += f2; p3 += f3;
                    }
                }
            }
        }
        float nd = normI[(size_t)r * N + n];
        a0 = fmaf(p0, nd, a0); a1 = fmaf(p1, nd, a1);
        a2 = fmaf(p2, nd, a2); a3 = fmaf(p3, nd, a3);
    }
    a0 += __shfl_xor(a0, 32, 64);
    a1 += __shfl_xor(a1, 32, 64);
    a2 += __shfl_xor(a2, 32, 64);
    a3 += __shfl_xor(a3, 32, 64);
    if (half == 0) {
        int col = q * 4;
        a0 += bias[col]     + bias[128 + col]     + bias[256 + col];
        a1 += bias[col + 1] + bias[128 + col + 1] + bias[256 + col + 1];
        a2 += bias[col + 2] + bias[128 + col + 2] + bias[256 + col + 2];
        a3 += bias[col + 3] + bias[128 + col + 3] + bias[256 + col + 3];
        if (RELU) {
            a0 = fmaxf(a0, 0.f); a1 = fmaxf(a1, 0.f);
            a2 = fmaxf(a2, 0.f); a3 = fmaxf(a3, 0.f);
        }
        if (BF16OUT) {
            uint2 pk;
            pk.x = (unsigned int)f2bf(a0) | ((unsigned int)f2bf(a1) << 16);
            pk.y = (unsigned int)f2bf(a2) | ((unsigned int)f2bf(a3) << 16);
            ((uint2*)out)[(size_t)n * 32 + q] = pk;
        } else {
            ((float4*)out)[(size_t)n * 32 + q] = make_float4(a0, a1, a2, a3);
        }
    }
}

extern "C" void kernel_launch(void* const* d_in, const int* in_sizes, int n_in,
                              void* d_out, int out_size, void* d_ws, size_t ws_size,
                              hipStream_t stream) {
    const float* x  = (const float*)d_in[0];
    const int* src  = (const int*)d_in[1];
    const int* dst  = (const int*)d_in[2];
    const float* W1 = (const float*)d_in[3];
    const float* b1 = (const float*)d_in[4];
    const float* W2 = (const float*)d_in[5];
    const float* b2 = (const float*)d_in[6];
    float* out = (float*)d_out;

    const int R = 3;
    int N = in_sizes[0] / 128;
    int E = in_sizes[1] / R;
    int RN = R * N, RE = R * E;
    int NB = (N + 1023) >> 10;
    int NB3 = 3 * NB;
    if (NB3 > MAXB) return;

    size_t h1b = (size_t)N * 128 * 2;          // bf16 hidden; aliases packed-pair buffer
    size_t Tb  = (size_t)R * N * 128 * 2;      // bf16 messages, all relations
    size_t ib  = (size_t)RN * 4;               // one int/float [R][N] array
    size_t bb  = (size_t)NB3 * CAP * 4;        // padded bucket
    size_t wb  = (size_t)2 * R * 16384 * 2;    // bf16 transposed weights
    size_t bcb = (size_t)((2 * NB3 * 4 + 255) & ~255);  // bincntO + bincntD
    if ((size_t)NB3 * CAP * 4 > h1b) return;             // pair (u32) fits in h1 alias
    if ((size_t)NB3 * CAP * 2 > (size_t)out_size) return; // srcbin (u16) fits in out alias
    if (ws_size < h1b + Tb + 4 * ib + bb + wb + bcb) return;

    char* w = (char*)d_ws;
    unsigned short* h1   = (unsigned short*)w;            w += h1b;
    unsigned short* T    = (unsigned short*)w;            w += Tb;
    unsigned int* cntI   = (unsigned int*)w;              w += ib;
    float* normO         = (float*)w;                     w += ib;
    float* normI         = (float*)w;                     w += ib;
    int* offs            = (int*)w;                       w += ib;
    int* bucket          = (int*)w;                       w += bb;
    unsigned short* WbfT = (unsigned short*)w;            w += wb;
    int* bincnt          = (int*)w;                       // [2][NB3]

    int* bincntO = bincnt;
    int* bincntD = bincnt + NB3;
    unsigned int* pair     = (unsigned int*)h1;   // dead before gather1 writes h1
    unsigned short* srcbin = (unsigned short*)d_out; // dead before gather2 writes out

    hipMemsetAsync(bincnt, 0, (size_t)2 * NB3 * 4, stream);

    wconv_kernel<<<(2 * R * 16384 + 255) / 256, 256, 0, stream>>>(W1, W2, WbfT, 2 * R * 16384);

    int pa = (RE + 4095) / 4096;
    int gb = (N + 63) / 64;
    int ngb = (N + 3) / 4;

    // mega: layer-1 gemm (no normO dependency) + dual src/dst binning
    gemm3_binA<<<gb + pa, 256, 0, stream>>>(x, WbfT, T, N, gb, src, dst,
                                            bincntO, bincntD, srcbin, pair, RE, E, N, NB);

    // fused: out-degree histogram (normO) + per-bin counting sort (cntI/normI/offs/bucket)
    histsort_kernel<<<2 * NB3, 256, 0, stream>>>(srcbin, bincntO, pair, bincntD,
                                                 normO, cntI, normI, offs, bucket, N, NB, NB3);

    gather_kernel<true, true, true><<<ngb, 256, 0, stream>>>(T, bucket, offs, cntI,
                                                             normI, normO, b1, h1, N);

    // layer 2
    gemm3_bf16<<<gb, 256, 0, stream>>>(h1, WbfT + (size_t)3 * 16384, normO, T, N);
    gather_kernel<false, false, false><<<ngb, 256, 0, stream>>>(T, bucket, offs, cntI,
                                                                normI, normO, b2, out, N);
}

// Round 6
// 463.092 us; speedup vs baseline: 1.0272x; 1.0272x over previous
//
#include <hip/hip_runtime.h>

typedef short s16x8 __attribute__((ext_vector_type(8)));
typedef float f32x4 __attribute__((ext_vector_type(4)));

#define LDW 136    // padded LDS row stride in shorts (128 + 8)
#define CAP 10240  // padded bin segment capacity (mean 8192, sigma~90 -> 22 sigma headroom)
#define MAXB 384   // max 3*NB bins supported (N <= 131072; also src must fit 20 bits)

__device__ __forceinline__ unsigned short f2bf(float x) {
    unsigned int u = __builtin_bit_cast(unsigned int, x);
    u = (u + 0x7fffu + ((u >> 16) & 1u)) >> 16;   // RNE
    return (unsigned short)u;
}
__device__ __forceinline__ float bf2f(unsigned int lo) {
    return __builtin_bit_cast(float, lo << 16);
}

// ---- W fp32 -> bf16, transposed: WbfT[which][n][k] = bf16(W[which][k][n]) ----
__global__ __launch_bounds__(256) void wconv_kernel(const float* __restrict__ W1,
                                                    const float* __restrict__ W2,
                                                    unsigned short* __restrict__ WbfT,
                                                    int total) {
    int idx = blockIdx.x * 256 + threadIdx.x;
    if (idx >= total) return;
    int which = idx >> 14;
    int k = (idx >> 7) & 127;
    int n = idx & 127;
    int outi = (idx & ~16383) | (n << 7) | k;
    const float* W = (which < 3) ? (W1 + (size_t)which * 16384)
                                 : (W2 + (size_t)(which - 3) * 16384);
    WbfT[outi] = f2bf(W[k * 128 + n]);
}

// ---- FUSED MEGA: blocks [0,gb) = layer-1 gemm3 (fp32 input, UNSCALED T out);
//      blocks [gb,..) = dual src+dst binning (edges held in regs, one pass) ----
__global__ __launch_bounds__(256) void gemm3_binA(const float* __restrict__ Xp,
                                                  const unsigned short* __restrict__ WbfT,
                                                  unsigned short* __restrict__ T,
                                                  int nrows, int gb,
                                                  const int* __restrict__ src,
                                                  const int* __restrict__ dst,
                                                  int* __restrict__ bincntO,
                                                  int* __restrict__ bincntD,
                                                  unsigned short* __restrict__ srcbin,
                                                  unsigned int* __restrict__ pair,
                                                  int RE, int E, int N, int NB) {
    __shared__ unsigned short Xl[64 * LDW];
    __shared__ unsigned short Wl[128 * LDW];
    int tid = threadIdx.x;

    if ((int)blockIdx.x >= gb) {
        // ---- dual-binning branch: src-bins (ushort s&1023) + dst-bins (packed u32) ----
        int* histS = (int*)Xl;            // MAXB ints
        int* histD = histS + MAXB;        // MAXB ints (fits in Xl: 3KB << 17.4KB)
        int ebase = ((int)blockIdx.x - gb) * 4096;
        int NB3 = 3 * NB;
        int vs[16], vd[16];
        for (int t = tid; t < 2 * MAXB; t += 256) histS[t] = 0;
        __syncthreads();
#pragma unroll
        for (int j = 0; j < 16; ++j) {
            int i = ebase + j * 256 + tid;
            vs[j] = 0; vd[j] = 0;
            if (i < RE) {
                vs[j] = src[i]; vd[j] = dst[i];
                int r = (i >= 2 * E) ? 2 : ((i >= E) ? 1 : 0);
                atomicAdd(&histS[r * NB + (vs[j] >> 10)], 1);
                atomicAdd(&histD[r * NB + (vd[j] >> 10)], 1);
            }
        }
        __syncthreads();
        for (int t = tid; t < NB3; t += 256) {
            int cS = histS[t]; histS[t] = cS ? atomicAdd(&bincntO[t], cS) : 0;
            int cD = histD[t]; histD[t] = cD ? atomicAdd(&bincntD[t], cD) : 0;
        }
        __syncthreads();
#pragma unroll
        for (int j = 0; j < 16; ++j) {
            int i = ebase + j * 256 + tid;
            if (i < RE) {
                int r = (i >= 2 * E) ? 2 : ((i >= E) ? 1 : 0);
                int gS = r * NB + (vs[j] >> 10);
                int pS = atomicAdd(&histS[gS], 1);
                if (pS < CAP) srcbin[(size_t)gS * CAP + pS] = (unsigned short)(vs[j] & 1023);
                int gD = r * NB + (vd[j] >> 10);
                int pD = atomicAdd(&histD[gD], 1);
                if (pD < CAP)
                    pair[(size_t)gD * CAP + pD] =
                        ((unsigned)(vd[j] & 1023) << 20) | (unsigned)vs[j];
            }
        }
        return;
    }

    // ---- gemm3 layer-1 branch (T written UNSCALED; normO applied in gather1) ----
    int row0 = blockIdx.x * 64;
#pragma unroll
    for (int j = 0; j < 8; ++j) {
        int f4 = tid + j * 256;
        int row = f4 >> 5;
        int k0 = (f4 & 31) * 4;
        int gr = row0 + row;
        float4 v = make_float4(0.f, 0.f, 0.f, 0.f);
        if (gr < nrows) v = ((const float4*)Xp)[(size_t)gr * 32 + (f4 & 31)];
        unsigned long long pk = (unsigned long long)f2bf(v.x)
                              | ((unsigned long long)f2bf(v.y) << 16)
                              | ((unsigned long long)f2bf(v.z) << 32)
                              | ((unsigned long long)f2bf(v.w) << 48);
        *(unsigned long long*)(&Xl[row * LDW + k0]) = pk;
    }
#pragma unroll
    for (int j = 0; j < 8; ++j) {
        int i = tid + j * 256;            // 2048 uint4 chunks = 128*128 shorts
        int row = i >> 4, c0 = (i & 15) * 8;
        *(uint4*)(Wl + row * LDW + c0) = ((const uint4*)WbfT)[i];
    }
    __syncthreads();

    int wave = tid >> 6, lane = tid & 63;
    int laneM = lane & 15, quad = lane >> 4;
    int m0 = wave * 16;

    s16x8 afr[4];
#pragma unroll
    for (int ks = 0; ks < 4; ++ks)
        afr[ks] = *(const s16x8*)(Xl + (m0 + laneM) * LDW + ks * 32 + quad * 8);

    for (int r = 0; r < 3; ++r) {
        f32x4 acc[8];
#pragma unroll
        for (int ct = 0; ct < 8; ++ct) acc[ct] = (f32x4){0.f, 0.f, 0.f, 0.f};
#pragma unroll
        for (int ks = 0; ks < 4; ++ks) {
            int k = ks * 32 + quad * 8;
#pragma unroll
            for (int ct = 0; ct < 8; ++ct) {
                s16x8 b = *(const s16x8*)(Wl + (ct * 16 + laneM) * LDW + k);
                acc[ct] = __builtin_amdgcn_mfma_f32_16x16x32_bf16(afr[ks], b, acc[ct], 0, 0, 0);
            }
        }
        unsigned short* Tr = T + (size_t)r * nrows * 128;
#pragma unroll
        for (int i = 0; i < 4; ++i) {
            int gr = row0 + m0 + quad * 4 + i;
            if (gr < nrows) {
#pragma unroll
                for (int ct = 0; ct < 8; ++ct)
                    Tr[(size_t)gr * 128 + ct * 16 + laneM] = f2bf(acc[ct][i]);
            }
        }
        if (r < 2) {
            __syncthreads();
#pragma unroll
            for (int j = 0; j < 8; ++j) {
                int i = tid + j * 256;
                int row = i >> 4, c0 = (i & 15) * 8;
                *(uint4*)(Wl + row * LDW + c0) =
                    ((const uint4*)(WbfT + (size_t)(r + 1) * 16384))[i];
            }
            __syncthreads();
        }
    }
}

// ---- FUSED: blocks [0,NB3) = out-degree histogram -> normO;
//      blocks [NB3,2*NB3) = per-(r,bin) LDS counting sort -> cntI/normI/offs/bucket ----
__global__ __launch_bounds__(256) void histsort_kernel(const unsigned short* __restrict__ srcbin,
                                                       const int* __restrict__ bincntO,
                                                       const unsigned int* __restrict__ pair,
                                                       const int* __restrict__ bincntD,
                                                       float* __restrict__ normO,
                                                       unsigned int* __restrict__ cntI,
                                                       float* __restrict__ normI,
                                                       int* __restrict__ offs,
                                                       int* __restrict__ bucket,
                                                       int N, int NB, int NB3) {
    __shared__ int lcnt[1024], lofs[1024], lcur[1024];
    __shared__ int ws[4];
    int tid = threadIdx.x;

    if ((int)blockIdx.x < NB3) {
        // ---- out-degree histogram branch ----
        int b = blockIdx.x;
        for (int i = tid; i < 1024; i += 256) lcnt[i] = 0;
        __syncthreads();
        int len = bincntO[b]; if (len > CAP) len = CAP;
        const unsigned short* seg = srcbin + (size_t)b * CAP;
        for (int e = tid; e < len; e += 256)
            atomicAdd(&lcnt[seg[e]], 1);
        __syncthreads();
        int r = b / NB, bin = b - r * NB;
        int node0 = bin << 10;
        for (int i = tid; i < 1024; i += 256) {
            int node = node0 + i;
            if (node < N)
                normO[(size_t)r * N + node] = rsqrtf(fmaxf((float)lcnt[i], 1.0f));
        }
        return;
    }

    // ---- counting-sort branch ----
    int b = blockIdx.x - NB3;
    for (int i = tid; i < 1024; i += 256) { lcnt[i] = 0; lcur[i] = 0; }
    __syncthreads();
    int len = bincntD[b]; if (len > CAP) len = CAP;
    const unsigned int* seg = pair + (size_t)b * CAP;
    for (int e = tid; e < len; e += 256)
        atomicAdd(&lcnt[seg[e] >> 20], 1);
    __syncthreads();
    // exclusive scan of lcnt[1024] -> lofs
    int i0 = tid * 4;
    int a0 = lcnt[i0], a1 = lcnt[i0 + 1], a2 = lcnt[i0 + 2], a3 = lcnt[i0 + 3];
    int tot = a0 + a1 + a2 + a3;
    int lane = tid & 63, w = tid >> 6;
    int x = tot;
#pragma unroll
    for (int d = 1; d < 64; d <<= 1) { int y = __shfl_up(x, d, 64); if (lane >= d) x += y; }
    if (lane == 63) ws[w] = x;
    __syncthreads();
    int wbase = 0;
    for (int k = 0; k < 4; ++k) if (k < w) wbase += ws[k];
    int pre = wbase + x - tot;
    lofs[i0] = pre;
    lofs[i0 + 1] = pre + a0;
    lofs[i0 + 2] = pre + a0 + a1;
    lofs[i0 + 3] = pre + a0 + a1 + a2;
    __syncthreads();
    int r = b / NB, bin = b - r * NB;
    int node0 = bin << 10;
    int base = b * CAP;
    for (int i = tid; i < 1024; i += 256) {
        int node = node0 + i;
        if (node < N) {
            int c = lcnt[i];
            cntI[(size_t)r * N + node]  = (unsigned int)c;
            normI[(size_t)r * N + node] = rsqrtf(fmaxf((float)c, 1.0f));
            offs[(size_t)r * N + node]  = base + lofs[i];
        }
    }
    for (int e = tid; e < len; e += 256) {
        unsigned int p = seg[e];
        int dl = p >> 20;
        int lr = atomicAdd(&lcur[dl], 1);
        bucket[(size_t)base + lofs[dl] + lr] = (int)(p & 0xFFFFFu);
    }
}

// ---- layer-2 gemm (bf16 input, normO applied in epilogue as before) ----
__global__ __launch_bounds__(256) void gemm3_bf16(const unsigned short* __restrict__ Xp,
                                                  const unsigned short* __restrict__ WbfT,
                                                  const float* __restrict__ normO,
                                                  unsigned short* __restrict__ T,
                                                  int nrows) {
    __shared__ unsigned short Xl[64 * LDW];
    __shared__ unsigned short Wl[128 * LDW];
    int tid = threadIdx.x;
    int row0 = blockIdx.x * 64;

#pragma unroll
    for (int j = 0; j < 8; ++j) {
        int f4 = tid + j * 256;
        int row = f4 >> 5;
        int k0 = (f4 & 31) * 4;
        int gr = row0 + row;
        uint2 v = make_uint2(0u, 0u);
        if (gr < nrows) v = ((const uint2*)Xp)[(size_t)gr * 32 + (f4 & 31)];
        *(uint2*)(&Xl[row * LDW + k0]) = v;
    }
#pragma unroll
    for (int j = 0; j < 8; ++j) {
        int i = tid + j * 256;
        int row = i >> 4, c0 = (i & 15) * 8;
        *(uint4*)(Wl + row * LDW + c0) = ((const uint4*)WbfT)[i];
    }
    __syncthreads();

    int wave = tid >> 6, lane = tid & 63;
    int laneM = lane & 15, quad = lane >> 4;
    int m0 = wave * 16;

    s16x8 afr[4];
#pragma unroll
    for (int ks = 0; ks < 4; ++ks)
        afr[ks] = *(const s16x8*)(Xl + (m0 + laneM) * LDW + ks * 32 + quad * 8);

    for (int r = 0; r < 3; ++r) {
        f32x4 acc[8];
#pragma unroll
        for (int ct = 0; ct < 8; ++ct) acc[ct] = (f32x4){0.f, 0.f, 0.f, 0.f};
#pragma unroll
        for (int ks = 0; ks < 4; ++ks) {
            int k = ks * 32 + quad * 8;
#pragma unroll
            for (int ct = 0; ct < 8; ++ct) {
                s16x8 b = *(const s16x8*)(Wl + (ct * 16 + laneM) * LDW + k);
                acc[ct] = __builtin_amdgcn_mfma_f32_16x16x32_bf16(afr[ks], b, acc[ct], 0, 0, 0);
            }
        }
        unsigned short* Tr = T + (size_t)r * nrows * 128;
        const float* nrm = normO + (size_t)r * nrows;
#pragma unroll
        for (int i = 0; i < 4; ++i) {
            int gr = row0 + m0 + quad * 4 + i;
            if (gr < nrows) {
                float sc = nrm[gr];
#pragma unroll
                for (int ct = 0; ct < 8; ++ct)
                    Tr[(size_t)gr * 128 + ct * 16 + laneM] = f2bf(acc[ct][i] * sc);
            }
        }
        if (r < 2) {
            __syncthreads();
#pragma unroll
            for (int j = 0; j < 8; ++j) {
                int i = tid + j * 256;
                int row = i >> 4, c0 = (i & 15) * 8;
                *(uint4*)(Wl + row * LDW + c0) =
                    ((const uint4*)(WbfT + (size_t)(r + 1) * 16384))[i];
            }
            __syncthreads();
        }
    }
}

// ---- gather (R4-proven structure): one wave per dst node, full-wave 256B row
// loads, x8 batching for MLP. NORMO: per-src scale loaded once per 64-edge
// block (L2-resident 1.2MB array), shfl-broadcast in the batch loop. ----
template <bool RELU, bool BF16OUT, bool NORMO>
__global__ __launch_bounds__(256) void gather_kernel(const unsigned short* __restrict__ T, // [R][N][128]
                                                     const int* __restrict__ bucket,       // padded bins
                                                     const int* __restrict__ offs,         // [R][N] ABSOLUTE
                                                     const unsigned int* __restrict__ cnt, // [R][N]
                                                     const float* __restrict__ normI,      // [R][N]
                                                     const float* __restrict__ normO,      // [R][N]
                                                     const float* __restrict__ bias,       // [R][128]
                                                     void* __restrict__ out,
                                                     int N) {
    int n = blockIdx.x * 4 + (threadIdx.x >> 6);
    if (n >= N) return;
    int lane = threadIdx.x & 63;
    float a0 = 0.f, a1 = 0.f;
    const float2* bv = (const float2*)bias;
#pragma unroll
    for (int r = 0; r < 3; ++r) {
        float p0 = 0.f, p1 = 0.f;
        int start = offs[(size_t)r * N + n];
        int c = (int)cnt[(size_t)r * N + n];
        const unsigned int* Tr = (const unsigned int*)(T + (size_t)r * N * 128);
        const float* nO = normO + (size_t)r * N;
        const int* bk = bucket + start;
        for (int base = 0; base < c; base += 64) {
            int m = min(64, c - base);
            int id = (lane < m) ? bk[base + lane] : 0;
            float nv = 0.f;
            if (NORMO) nv = (lane < m) ? nO[id] : 0.f;
            for (int jj = 0; jj < m; jj += 8) {
                int mm = m - jj;                      // wave-uniform
                unsigned int v[8];
#pragma unroll
                for (int u = 0; u < 8; ++u) {
                    int s2 = __shfl(id, jj + u, 64);
                    v[u] = (u < mm) ? Tr[(size_t)s2 * 64 + lane] : 0u;
                }
#pragma unroll
                for (int u = 0; u < 8; ++u) {
                    float f0 = bf2f(v[u] & 0xffffu);
                    float f1 = bf2f(v[u] >> 16);
                    if (NORMO) {
                        float sc = __shfl(nv, jj + u, 64);
                        p0 = fmaf(sc, f0, p0);
                        p1 = fmaf(sc, f1, p1);
                    } else {
                        p0 += f0; p1 += f1;
                    }
                }
            }
        }
        float nd = normI[(size_t)r * N + n];
        float2 bb = bv[r * 64 + lane];
        a0 += p0 * nd + bb.x;
        a1 += p1 * nd + bb.y;
    }
    if (RELU) { a0 = fmaxf(a0, 0.f); a1 = fmaxf(a1, 0.f); }
    if (BF16OUT) {
        unsigned int pk = (unsigned int)f2bf(a0) | ((unsigned int)f2bf(a1) << 16);
        ((unsigned int*)out)[(size_t)n * 64 + lane] = pk;
    } else {
        ((float2*)((float*)out + (size_t)n * 128))[lane] = make_float2(a0, a1);
    }
}

extern "C" void kernel_launch(void* const* d_in, const int* in_sizes, int n_in,
                              void* d_out, int out_size, void* d_ws, size_t ws_size,
                              hipStream_t stream) {
    const float* x  = (const float*)d_in[0];
    const int* src  = (const int*)d_in[1];
    const int* dst  = (const int*)d_in[2];
    const float* W1 = (const float*)d_in[3];
    const float* b1 = (const float*)d_in[4];
    const float* W2 = (const float*)d_in[5];
    const float* b2 = (const float*)d_in[6];
    float* out = (float*)d_out;

    const int R = 3;
    int N = in_sizes[0] / 128;
    int E = in_sizes[1] / R;
    int RN = R * N, RE = R * E;
    int NB = (N + 1023) >> 10;
    int NB3 = 3 * NB;
    if (NB3 > MAXB) return;

    size_t h1b = (size_t)N * 128 * 2;          // bf16 hidden; aliases packed-pair buffer
    size_t Tb  = (size_t)R * N * 128 * 2;      // bf16 messages, all relations
    size_t ib  = (size_t)RN * 4;               // one int/float [R][N] array
    size_t bb  = (size_t)NB3 * CAP * 4;        // padded bucket
    size_t wb  = (size_t)2 * R * 16384 * 2;    // bf16 transposed weights
    size_t bcb = (size_t)((2 * NB3 * 4 + 255) & ~255);  // bincntO + bincntD
    if ((size_t)NB3 * CAP * 4 > h1b) return;             // pair (u32) fits in h1 alias
    if ((size_t)NB3 * CAP * 2 > (size_t)out_size) return; // srcbin (u16) fits in out alias
    if (ws_size < h1b + Tb + 4 * ib + bb + wb + bcb) return;

    char* w = (char*)d_ws;
    unsigned short* h1   = (unsigned short*)w;            w += h1b;
    unsigned short* T    = (unsigned short*)w;            w += Tb;
    unsigned int* cntI   = (unsigned int*)w;              w += ib;
    float* normO         = (float*)w;                     w += ib;
    float* normI         = (float*)w;                     w += ib;
    int* offs            = (int*)w;                       w += ib;
    int* bucket          = (int*)w;                       w += bb;
    unsigned short* WbfT = (unsigned short*)w;            w += wb;
    int* bincnt          = (int*)w;                       // [2][NB3]

    int* bincntO = bincnt;
    int* bincntD = bincnt + NB3;
    unsigned int* pair     = (unsigned int*)h1;      // dead before gather1 writes h1
    unsigned short* srcbin = (unsigned short*)d_out; // dead before gather2 writes out

    hipMemsetAsync(bincnt, 0, (size_t)2 * NB3 * 4, stream);

    wconv_kernel<<<(2 * R * 16384 + 255) / 256, 256, 0, stream>>>(W1, W2, WbfT, 2 * R * 16384);

    int pa = (RE + 4095) / 4096;
    int gb = (N + 63) / 64;
    int ngb = (N + 3) / 4;

    // mega: layer-1 gemm (no normO dependency) + dual src/dst binning
    gemm3_binA<<<gb + pa, 256, 0, stream>>>(x, WbfT, T, N, gb, src, dst,
                                            bincntO, bincntD, srcbin, pair, RE, E, N, NB);

    // fused: out-degree histogram (normO) + per-bin counting sort (cntI/normI/offs/bucket)
    histsort_kernel<<<2 * NB3, 256, 0, stream>>>(srcbin, bincntO, pair, bincntD,
                                                 normO, cntI, normI, offs, bucket, N, NB, NB3);

    gather_kernel<true, true, true><<<ngb, 256, 0, stream>>>(T, bucket, offs, cntI,
                                                             normI, normO, b1, h1, N);

    // layer 2
    gemm3_bf16<<<gb, 256, 0, stream>>>(h1, WbfT + (size_t)3 * 16384, normO, T, N);
    gather_kernel<false, false, false><<<ngb, 256, 0, stream>>>(T, bucket, offs, cntI,
                                                                normI, normO, b2, out, N);
}